// Round 7
// baseline (1404.146 us; speedup 1.0000x reference)
//
#include <hip/hip_runtime.h>
#include <hip/hip_bf16.h>
#include <math.h>

typedef __hip_bfloat16 bf16;
typedef short short8 __attribute__((ext_vector_type(8)));
typedef float floatx4 __attribute__((ext_vector_type(4)));

// problem constants
static const int B2   = 2;
static const int TT   = 16;
static const int NTK  = 1024;
static const int CTK  = 256;
static const int QD   = 320;
static const int INNR = 512;
static const int CD   = 1024;
#define SCALE_ 0.125f

__device__ __forceinline__ ushort f2bu(float x){
  bf16 h = __float2bfloat16(x);
  return *reinterpret_cast<ushort*>(&h);
}

// ======================================================================================
// LDS tile layout (per 32-k tile, rows x 32 bf16, NO pad):
//   us_off(row, q, t) = row*32 + ((q + (row>>1))&3)*8 + t     q = 16B chunk 0..3
// Conflict-free verified (R5/R6: SQ_LDS_BANK_CONFLICT = 0 on this pattern).
// Staging: T14 reg-based, now 2-DEEP (tile i+2 loads issued a full iteration before
// their ds_write) -> global latency covered by barrier + MFMA + one full K-step.
// ======================================================================================

// bf16 rows: row-major [rows][ld(us)], NV=2 -> 128 rows, NV=1 -> 64 rows.
template<int NV>
struct StBf {
  const ushort* src; int ld; int tid;
  short8 r[NV];
  __device__ __forceinline__ void load(int k0){
#pragma unroll
    for(int v=0;v<NV;v++){
      int idx=tid+v*256, rr=idx>>2, kq=idx&3;
      r[v] = *(const short8*)&src[(size_t)rr*ld + k0 + kq*8];
    }
  }
  __device__ __forceinline__ void store(ushort* dst){
#pragma unroll
    for(int v=0;v<NV;v++){
      int idx=tid+v*256, rr=idx>>2, kq=idx&3;
      *(short8*)&dst[rr*32 + ((kq+(rr>>1))&3)*8] = r[v];
    }
  }
};

// f32 rows (A of g_kv): reg-stage + cvt, swizzled ds_write
struct StT128 {
  const float* src; int ld; int tid;
  float4 r[4];
  __device__ __forceinline__ void load(int k0){
#pragma unroll
    for(int i=0;i<4;i++){
      int f4=tid+i*256, rr=f4>>3, kq=f4&7;
      r[i] = *(const float4*)(src + (size_t)rr*ld + k0 + kq*4);
    }
  }
  __device__ __forceinline__ void store(ushort* dst){
#pragma unroll
    for(int i=0;i<4;i++){
      int f4=tid+i*256, rr=f4>>3, kq=f4&7;
      int s=((kq>>1)+(rr>>1))&3;
      float4 v=r[i];
      ushort4 u={f2bu(v.x),f2bu(v.y),f2bu(v.z),f2bu(v.w)};
      *(ushort4*)&dst[rr*32 + s*8 + (kq&1)*4]=u;
    }
  }
};

// pose gather (A of g_atok): A[m][kk] = base[(k0+kk)*T*N + m], f32 + cvt, swizzled write
struct StAtok {
  const float* base; int tid;
  float r[16];
  __device__ __forceinline__ void load(int k0){
#pragma unroll
    for(int i=0;i<16;i++){
      int e=tid+i*256, m=e&127, kk=e>>7;
      r[i]=base[(size_t)(k0+kk)*(TT*NTK) + m];
    }
  }
  __device__ __forceinline__ void store(ushort* dst){
#pragma unroll
    for(int i=0;i<16;i++){
      int e=tid+i*256, m=e&127, kk=e>>7;
      int s=((kk>>3)+(m>>1))&3;
      dst[m*32 + s*8 + (kk&7)]=f2bu(r[i]);
    }
  }
};

// ============================ MFMA tile compute (swizzled read) ============================
template<int NT>
__device__ __forceinline__ void mfma_tiles(const ushort* As, const ushort* Bs,
    floatx4 (&acc)[4][NT], int mOff, int nOff, int lane15, int quad){
  short8 af[4], bfm[NT];
  #pragma unroll
  for(int i=0;i<4;i++){
    int ar = mOff + i*16 + lane15;
    af[i] = *(const short8*)&As[ar*32 + ((quad + (ar>>1))&3)*8];
  }
  #pragma unroll
  for(int j=0;j<NT;j++){
    int br = nOff + j*16 + lane15;
    bfm[j] = *(const short8*)&Bs[br*32 + ((quad + (br>>1))&3)*8];
  }
  #pragma unroll
  for(int i=0;i<4;i++)
    #pragma unroll
    for(int j=0;j<NT;j++)
      acc[i][j] = __builtin_amdgcn_mfma_f32_16x16x32_bf16(af[i], bfm[j], acc[i][j], 0, 0, 0);
}

template<int NT>
__device__ __forceinline__ void zero_acc(floatx4 (&acc)[4][NT]){
  floatx4 z = {0.f,0.f,0.f,0.f};
  #pragma unroll
  for(int i=0;i<4;i++)
    #pragma unroll
    for(int j=0;j<NT;j++) acc[i][j]=z;
}

// ===== 2-deep double-buffered K-loop (nk EVEN for all call sites: 8..40).
// Even iter i reads As0/Bs0; odd reads As1/Bs1. Loads for tile i+2 issue one full
// iteration before their ds_write. Store always targets the buffer not being read;
// one barrier separates every write from its read (same discipline as 1-deep core). =====
template<int NT, class SA, class SB>
__device__ __forceinline__ void core_db(SA& sa0, SA& sa1, SB& sb0, SB& sb1, int K,
    ushort* As0, ushort* As1, ushort* Bs0, ushort* Bs1,
    floatx4 (&acc)[4][NT], int mOff, int nOff, int lane15, int quad){
  const int nk = K>>5;
  sa0.load(0);  sb0.load(0);
  sa1.load(32); sb1.load(32);
  sa0.store(As0); sb0.store(Bs0);
  for(int i=0;i<nk;i+=2){
    // even iter i: compute tile i from As0/Bs0
    if(i+2<nk){ sa0.load((i+2)<<5); sb0.load((i+2)<<5); }   // regs freed by last store
    __syncthreads();
    mfma_tiles<NT>(As0,Bs0,acc,mOff,nOff,lane15,quad);
    sa1.store(As1); sb1.store(Bs1);                          // tile i+1 (nk even => exists)
    // odd iter i+1: compute tile i+1 from As1/Bs1
    if(i+3<nk){ sa1.load((i+3)<<5); sb1.load((i+3)<<5); }
    __syncthreads();
    mfma_tiles<NT>(As1,Bs1,acc,mOff,nOff,lane15,quad);
    if(i+2<nk){ sa0.store(As0); sb0.store(Bs0); }            // tile i+2
  }
}

#define GEMM_IDS(NT_) \
  const int tid=threadIdx.x, w=tid>>6, lane15=tid&15, quad=(tid>>4)&3; \
  const int mOff=(w&1)*64, nOff=(w>>1)*(NT_*16);
#define EPI(NT_) \
  _Pragma("unroll") for(int i=0;i<4;i++) \
  _Pragma("unroll") for(int j=0;j<NT_;j++) \
  _Pragma("unroll") for(int r=0;r<4;r++)
#define ROWG (mOff + i*16 + quad*4 + r)
#define COLG (nOff + j*16 + lane15)

// ---------------- one-time: W[K][N] f32 -> WT[N][K] bf16 (tiled transpose) ----------------
__global__ void __launch_bounds__(256) k_wtrans(const float* __restrict__ W, ushort* __restrict__ WT,
                                                int K, int N){
  __shared__ float t[64][65];
  const int kB = blockIdx.y*64, nB = blockIdx.x*64;
  for(int e=threadIdx.x; e<4096; e+=256){
    int r=e>>6, c=e&63;
    t[r][c] = W[(size_t)(kB+r)*N + nB+c];
  }
  __syncthreads();
  for(int e=threadIdx.x; e<4096; e+=256){
    int r=e>>6, c=e&63;
    WT[(size_t)(nB+r)*K + kB+c] = f2bu(t[c][r]);
  }
}

// ---------------- LN-apply -> bf16 rows ----------------
__global__ void k_ln(const float* __restrict__ hs, const float* __restrict__ w,
                     const float* __restrict__ b, ushort* __restrict__ out, int row0){
  const int r = blockIdx.x, lane = threadIdx.x;   // 64 threads
  const float* hr = hs + (size_t)(row0+r)*QD;
  float s=0.f, s2=0.f;
  #pragma unroll
  for(int j=0;j<5;j++){ float v=hr[j*64+lane]; s+=v; s2+=v*v; }
  #pragma unroll
  for(int o=32;o;o>>=1){ s+=__shfl_down(s,o); s2+=__shfl_down(s2,o); }
  s = __shfl(s,0); s2 = __shfl(s2,0);
  float mu=s*(1.f/320.f);
  float var=s2*(1.f/320.f)-mu*mu;
  float rs=rsqrtf(var+1e-5f);
  #pragma unroll
  for(int j=0;j<5;j++){
    int c=j*64+lane;
    out[(size_t)r*QD + c] = f2bu((hr[c]-mu)*rs*w[c]+b[c]);
  }
}

// ---------------- merged kv projection: z=(b, k/v)  (M=1024,N=512,K=1024) ----------------
__global__ void __launch_bounds__(256) g_kv(const float* __restrict__ A,
                                            const ushort* __restrict__ wkT, const ushort* __restrict__ wvT,
                                            ushort* __restrict__ kbf, float* __restrict__ vb,
                                            ushort* __restrict__ vbT){
  __shared__ ushort As[2][128*32], Bs[2][128*32];
  GEMM_IDS(4)
  const int z=blockIdx.z, b=z>>1, isv=z&1;
  const ushort* BT = (isv ? wvT : wkT) + (size_t)b*524288;
  const int rB=blockIdx.y*128, cB=blockIdx.x*128;
  floatx4 acc[4][4]; zero_acc<4>(acc);
  StT128 sa0{A + (size_t)rB*CD, CD, tid}, sa1{A + (size_t)rB*CD, CD, tid};
  StBf<2> sb0{BT + (size_t)cB*CD, CD, tid}, sb1{BT + (size_t)cB*CD, CD, tid};
  core_db<4>(sa0, sa1, sb0, sb1, CD, As[0],As[1],Bs[0],Bs[1], acc, mOff,nOff,lane15,quad);
  if(!isv){
    ushort* kb = kbf + (size_t)b*524288;
    EPI(4){ kb[(size_t)(rB+ROWG)*INNR + cB+COLG] = f2bu(acc[i][j][r]); }
  }else{
    float* vf = vb + (size_t)b*524288;
    ushort* vT = vbT + (size_t)b*524288;
    EPI(4){
      int row=rB+ROWG, col=cB+COLG;
      float v=acc[i][j][r];
      vf[(size_t)row*INNR + col] = v;
      vT[((size_t)(row>>8)*INNR + col)*CTK + (row&255)] = f2bu(v);
    }
  }
}

// ---------------- a_tok: atok[z] = pose_t[pt0+z] @ Wa  (M=1024,N=512,K=320) ----------------
__global__ void __launch_bounds__(256) g_atok(const float* __restrict__ pose, const ushort* __restrict__ WaT,
                                              ushort* __restrict__ atok, int pt0){
  __shared__ ushort As[2][128*32], Bs[2][128*32];
  GEMM_IDS(4)
  const int z=blockIdx.z, pt=pt0+z, bb=pt>>4, t=pt&15;
  const int rB=blockIdx.y*128, cB=blockIdx.x*128;
  floatx4 acc[4][4]; zero_acc<4>(acc);
  const float* pbase = pose + ((size_t)(bb*QD)*TT + t)*NTK + rB;
  StAtok sa0{pbase, tid}, sa1{pbase, tid};
  StBf<2> sb0{WaT + (size_t)cB*QD, QD, tid}, sb1{WaT + (size_t)cB*QD, QD, tid};
  core_db<4>(sa0, sa1, sb0, sb1, QD, As[0],As[1],Bs[0],Bs[1], acc, mOff,nOff,lane15,quad);
  EPI(4){ atok[((size_t)z*NTK + rB+ROWG)*INNR + cB+COLG] = f2bu(acc[i][j][r]); }
}

// ---------------- agent logits (NT) + scale + bias  (M=1024,N=256,K=512) ----------------
__global__ void __launch_bounds__(256) g_logits(const ushort* __restrict__ atok, const ushort* __restrict__ kbf,
                                                const float* __restrict__ abias, float* __restrict__ lgC, int pt0){
  __shared__ ushort As[2][128*32], Bs[2][128*32];
  GEMM_IDS(4)
  const int z=blockIdx.z, zp=z>>1, c=z&1, pt=pt0+zp, bb=pt>>4;
  const int rB=blockIdx.y*128, cB=blockIdx.x*128;
  floatx4 acc[4][4]; zero_acc<4>(acc);
  const ushort* ap = atok + ((size_t)zp*NTK + rB)*INNR;
  const ushort* bp = kbf + (size_t)(bb*512 + 2*cB + c)*INNR;
  StBf<2> sa0{ap, INNR, tid}, sa1{ap, INNR, tid};
  StBf<2> sb0{bp, 2*INNR, tid}, sb1{bp, 2*INNR, tid};
  core_db<4>(sa0, sa1, sb0, sb1, INNR, As[0],As[1],Bs[0],Bs[1], acc, mOff,nOff,lane15,quad);
  float* Cz = lgC + (size_t)(zp*2+c)*NTK*CTK;
  EPI(4){
    int row=rB+ROWG, col=cB+COLG;
    Cz[(size_t)row*CTK + col] = acc[i][j][r]*SCALE_ + abias[(size_t)row*CTK + col];
  }
}

// ---------------- PV + frame max (NT via vT) + transposed bf16 out  (M=1024,N=512,K=256) ----
__global__ void __launch_bounds__(256) g_pvmax(const ushort* __restrict__ lg_us, const ushort* __restrict__ vT,
                                               ushort* __restrict__ akvT, int pt0){
  __shared__ ushort As[2][128*32], Bs[2][128*32];
  GEMM_IDS(4)
  const int zp=blockIdx.z, pt=pt0+zp, bb=pt>>4;
  const int rB=blockIdx.y*128, cB=blockIdx.x*128;
  floatx4 best[4][4]; zero_acc<4>(best);
  floatx4 acc[4][4];
  for(int c=0;c<2;c++){
    if(c) __syncthreads();
    zero_acc<4>(acc);
    const ushort* ap = lg_us + ((size_t)(zp*2+c)*NTK + rB)*INNR;   // in-place bf16, stride 512us
    const ushort* bp = vT + ((size_t)(bb*2+c)*INNR + cB)*CTK;
    StBf<2> sa0{ap, INNR, tid}, sa1{ap, INNR, tid};
    StBf<2> sb0{bp, CTK, tid}, sb1{bp, CTK, tid};
    core_db<4>(sa0, sa1, sb0, sb1, CTK, As[0],As[1],Bs[0],Bs[1], acc, mOff,nOff,lane15,quad);
    if(c==0){
      #pragma unroll
      for(int i=0;i<4;i++)
        #pragma unroll
        for(int j=0;j<4;j++) best[i][j]=acc[i][j];
    }else{
      EPI(4){ best[i][j][r] = fmaxf(best[i][j][r], acc[i][j][r]); }
    }
  }
  #pragma unroll
  for(int i=0;i<4;i++)
    #pragma unroll
    for(int j=0;j<4;j++){
      int col = cB + nOff + j*16 + lane15;
      int row0 = rB + mOff + i*16 + quad*4;
      ushort4 u = { f2bu(best[i][j][0]), f2bu(best[i][j][1]), f2bu(best[i][j][2]), f2bu(best[i][j][3]) };
      *(ushort4*)&akvT[((size_t)zp*INNR + col)*NTK + row0] = u;
    }
}

// ---------------- q = LNh @ Wq  (rows = S*1024, N=512, K=320) ----------------
__global__ void __launch_bounds__(256) g_q(const ushort* __restrict__ lnh, const ushort* __restrict__ WqT,
                                           ushort* __restrict__ qb){
  __shared__ ushort As[2][128*32], Bs[2][128*32];
  GEMM_IDS(4)
  const int rB=blockIdx.y*128, cB=blockIdx.x*128;
  floatx4 acc[4][4]; zero_acc<4>(acc);
  const ushort* ap = lnh + (size_t)rB*QD;
  const ushort* bp = WqT + (size_t)cB*QD;
  StBf<2> sa0{ap, QD, tid}, sa1{ap, QD, tid};
  StBf<2> sb0{bp, QD, tid}, sb1{bp, QD, tid};
  core_db<4>(sa0, sa1, sb0, sb1, QD, As[0],As[1],Bs[0],Bs[1], acc, mOff,nOff,lane15,quad);
  EPI(4){ qb[(size_t)(rB+ROWG)*INNR + cB+COLG] = f2bu(acc[i][j][r]); }
}

// ---------------- query logits (NT) + scale + qbias  (M=1024,N=1024,K=512) ----------------
__global__ void __launch_bounds__(256) g_aql(const ushort* __restrict__ qb, const ushort* __restrict__ atok,
                                             const float* __restrict__ qbias, float* __restrict__ D){
  __shared__ ushort As[2][128*32], Bs[2][128*32];
  GEMM_IDS(4)
  const int z=blockIdx.z;
  const int rB=blockIdx.y*128, cB=blockIdx.x*128;
  floatx4 acc[4][4]; zero_acc<4>(acc);
  const ushort* ap = qb + ((size_t)z*NTK + rB)*INNR;
  const ushort* bp = atok + ((size_t)z*NTK + cB)*INNR;
  StBf<2> sa0{ap, INNR, tid}, sa1{ap, INNR, tid};
  StBf<2> sb0{bp, INNR, tid}, sb1{bp, INNR, tid};
  core_db<4>(sa0, sa1, sb0, sb1, INNR, As[0],As[1],Bs[0],Bs[1], acc, mOff,nOff,lane15,quad);
  float* Dz = D + (size_t)z*NTK*NTK;
  EPI(4){
    int row=rB+ROWG, col=cB+COLG;
    Dz[(size_t)row*NTK + col] = acc[i][j][r]*SCALE_ + qbias[(size_t)row*NTK + col];
  }
}

// ---------------- x = aq @ akv + v_tok  (M=1024,N=512,K=1024) ----------------
__global__ void __launch_bounds__(256) g_aqpv(const float* __restrict__ D, const ushort* __restrict__ akvT,
                                              const float* __restrict__ vt, ushort* __restrict__ xb, int pt0){
  __shared__ ushort As[2][128*32], Bs[2][128*32];
  GEMM_IDS(4)
  const int z=blockIdx.z, pt=pt0+z, bb=pt>>4;
  const int rB=blockIdx.y*128, cB=blockIdx.x*128;
  floatx4 acc[4][4]; zero_acc<4>(acc);
  const ushort* ap = (const ushort*)D + (size_t)z*2097152 + (size_t)rB*2048;  // in-place bf16 rows
  const ushort* bp = akvT + ((size_t)z*INNR + cB)*NTK;
  StBf<2> sa0{ap, 2048, tid}, sa1{ap, 2048, tid};
  StBf<2> sb0{bp, NTK, tid}, sb1{bp, NTK, tid};
  core_db<4>(sa0, sa1, sb0, sb1, NTK, As[0],As[1],Bs[0],Bs[1], acc, mOff,nOff,lane15,quad);
  EPI(4){
    int row=rB+ROWG, col=cB+COLG;
    xb[((size_t)z*NTK + row)*INNR + col] = f2bu(acc[i][j][r] + vt[((size_t)bb*NTK + row)*INNR + col]);
  }
}

// ---------------- hs += x @ Wo (BN=64)  (rows = S*1024, N=320, K=512) ----------------
__global__ void __launch_bounds__(256) g_wo(const ushort* __restrict__ xb, const ushort* __restrict__ WoT,
                                            float* __restrict__ hs, int row0){
  __shared__ ushort As[2][128*32], Bs[2][64*32];
  GEMM_IDS(2)
  const int rB=blockIdx.y*128, cB=blockIdx.x*64;
  floatx4 acc[4][2]; zero_acc<2>(acc);
  const ushort* ap = xb + (size_t)rB*INNR;
  const ushort* bp = WoT + (size_t)cB*INNR;
  StBf<2> sa0{ap, INNR, tid}, sa1{ap, INNR, tid};
  StBf<1> sb0{bp, INNR, tid}, sb1{bp, INNR, tid};
  core_db<2>(sa0, sa1, sb0, sb1, INNR, As[0],As[1],Bs[0],Bs[1], acc, mOff,nOff,lane15,quad);
  EPI(2){
    size_t o = (size_t)(row0+rB+ROWG)*QD + cB+COLG;
    hs[o] = hs[o] + acc[i][j][r];
  }
}

// ---------------- FF1 GEGLU (dual-B, BN=64)  (rows = S*1024, N=1280, K=320) ----------------
__global__ void __launch_bounds__(256) g_ff1(const ushort* __restrict__ lnh, const ushort* __restrict__ W1T,
    const float* __restrict__ b1, ushort* __restrict__ G){
  __shared__ ushort As[2][128*32], Ba[2][64*32], Bg[2][64*32];
  GEMM_IDS(2)
  const int rB=blockIdx.y*128, cB=blockIdx.x*64;
  floatx4 accA[4][2], accG[4][2]; zero_acc<2>(accA); zero_acc<2>(accG);
  const ushort* ap = lnh + (size_t)rB*QD;
  const ushort* p1 = W1T + (size_t)cB*QD;
  const ushort* p2 = W1T + (size_t)(1280+cB)*QD;
  StBf<2> sa0{ap, QD, tid}, sa1{ap, QD, tid};
  StBf<1> s10{p1, QD, tid}, s11{p1, QD, tid};
  StBf<1> s20{p2, QD, tid}, s21{p2, QD, tid};
  const int nk = QD>>5;  // 10 (even)
  sa0.load(0);  s10.load(0);  s20.load(0);
  sa1.load(32); s11.load(32); s21.load(32);
  sa0.store(As[0]); s10.store(Ba[0]); s20.store(Bg[0]);
  for(int i=0;i<nk;i+=2){
    if(i+2<nk){ sa0.load((i+2)<<5); s10.load((i+2)<<5); s20.load((i+2)<<5); }
    __syncthreads();
    mfma_tiles<2>(As[0],Ba[0],accA,mOff,nOff,lane15,quad);
    mfma_tiles<2>(As[0],Bg[0],accG,mOff,nOff,lane15,quad);
    sa1.store(As[1]); s11.store(Ba[1]); s21.store(Bg[1]);
    if(i+3<nk){ sa1.load((i+3)<<5); s11.load((i+3)<<5); s21.load((i+3)<<5); }
    __syncthreads();
    mfma_tiles<2>(As[1],Ba[1],accA,mOff,nOff,lane15,quad);
    mfma_tiles<2>(As[1],Bg[1],accG,mOff,nOff,lane15,quad);
    if(i+2<nk){ sa0.store(As[0]); s10.store(Ba[0]); s20.store(Bg[0]); }
  }
  EPI(2){
    int n = cB+COLG;
    float a = accA[i][j][r] + b1[n];
    float g = accG[i][j][r] + b1[1280+n];
    G[(size_t)(rB+ROWG)*1280 + n] = f2bu(a*0.5f*g*(1.0f+erff(g*0.70710678f)));
  }
}

// ---------------- FF2 + bias + residual  (rows = S*1024, N=320, K=1280) ----------------
__global__ void __launch_bounds__(256) g_ff2(const ushort* __restrict__ G, const ushort* __restrict__ W2T,
    const float* __restrict__ b2v, float* __restrict__ hs, int row0){
  __shared__ ushort As[2][128*32], Bs[2][64*32];
  GEMM_IDS(2)
  const int rB=blockIdx.y*128, cB=blockIdx.x*64;
  floatx4 acc[4][2]; zero_acc<2>(acc);
  const ushort* ap = G + (size_t)rB*1280;
  const ushort* bp = W2T + (size_t)cB*1280;
  StBf<2> sa0{ap, 1280, tid}, sa1{ap, 1280, tid};
  StBf<1> sb0{bp, 1280, tid}, sb1{bp, 1280, tid};
  core_db<2>(sa0, sa1, sb0, sb1, 1280, As[0],As[1],Bs[0],Bs[1], acc, mOff,nOff,lane15,quad);
  EPI(2){
    int col = cB+COLG;
    size_t o = (size_t)(row0+rB+ROWG)*QD + col;
    hs[o] = acc[i][j][r] + b2v[col] + hs[o];
  }
}

// ---------------- softmax over rows of 256: f32 in, bf16 out (in-place row head) ----------------
__global__ void k_softmax256(float* __restrict__ buf){
  __shared__ float red[8];
  const int tid=threadIdx.x;
  size_t row=blockIdx.x;
  float x = buf[row*256+tid];
  float m = x;
  #pragma unroll
  for(int o=32;o;o>>=1) m=fmaxf(m,__shfl_down(m,o));
  if((tid&63)==0) red[tid>>6]=m;
  __syncthreads();
  if(tid==0) red[4]=fmaxf(fmaxf(red[0],red[1]),fmaxf(red[2],red[3]));
  __syncthreads();
  float M=red[4];
  float e=__expf(x-M);
  float s=e;
  #pragma unroll
  for(int o=32;o;o>>=1) s+=__shfl_down(s,o);
  if((tid&63)==0) red[tid>>6]=s;
  __syncthreads();
  if(tid==0) red[5]=red[0]+red[1]+red[2]+red[3];
  __syncthreads();
  ((ushort*)buf)[row*512 + tid] = f2bu(e/red[5]);
}

// ---------------- softmax over rows of 1024: f32 in, bf16 out (in-place row head) ----------------
__global__ void k_softmax1024(float* __restrict__ buf){
  __shared__ float red[8];
  const int tid=threadIdx.x;
  size_t row=blockIdx.x;
  float4* p = (float4*)(buf + row*1024);
  float4 v = p[tid];
  float m = fmaxf(fmaxf(v.x,v.y),fmaxf(v.z,v.w));
  #pragma unroll
  for(int o=32;o;o>>=1) m=fmaxf(m,__shfl_down(m,o));
  if((tid&63)==0) red[tid>>6]=m;
  __syncthreads();
  if(tid==0) red[4]=fmaxf(fmaxf(red[0],red[1]),fmaxf(red[2],red[3]));
  __syncthreads();
  float M=red[4];
  v.x=__expf(v.x-M); v.y=__expf(v.y-M); v.z=__expf(v.z-M); v.w=__expf(v.w-M);
  float s=v.x+v.y+v.z+v.w;
  #pragma unroll
  for(int o=32;o;o>>=1) s+=__shfl_down(s,o);
  if((tid&63)==0) red[tid>>6]=s;
  __syncthreads();
  if(tid==0) red[5]=red[0]+red[1]+red[2]+red[3];
  __syncthreads();
  float inv=1.0f/red[5];
  ushort4 u = { f2bu(v.x*inv), f2bu(v.y*inv), f2bu(v.z*inv), f2bu(v.w*inv) };
  *(ushort4*)((ushort*)buf + row*2048 + (size_t)tid*4) = u;
}

// ---------------- depthwise 3x3 conv (SAME) + max over frames ----------------
__global__ void k_conv(const float* __restrict__ vbuf, const float* __restrict__ w3,
                       const float* __restrict__ wb, float* __restrict__ vm){
  int idx = blockIdx.x*256+threadIdx.x;
  if(idx >= B2*CTK*INNR) return;
  int e = idx & 511, hw = (idx>>9)&255, b = idx>>17;
  int h = hw>>4, w = hw&15;
  float wt[9];
  #pragma unroll
  for(int q=0;q<9;q++) wt[q]=w3[e*9+q];
  float bias = wb[e];
  float best=0.f;
  for(int c=0;c<2;c++){
    float s = bias;
    #pragma unroll
    for(int dy=-1;dy<=1;dy++)
      #pragma unroll
      for(int dx=-1;dx<=1;dx++){
        int hh=h+dy, ww=w+dx;
        if(hh>=0&&hh<16&&ww>=0&&ww<16)
          s += wt[(dy+1)*3+(dx+1)]*vbuf[((size_t)(b*2+c)*CTK + hh*16+ww)*INNR + e];
      }
    best = c ? fmaxf(best,s) : s;
  }
  vm[((size_t)b*CTK + hw)*INNR + e] = best;
}

// ---------------- bilinear x2 upsample (half-pixel, edge clamp) ----------------
__device__ __forceinline__ void up_wt(int i, int& j0, int& j1, float& w){
  float s = 0.5f*i - 0.25f;
  float f = floorf(s);
  w = s - f;
  int a = (int)f;
  j0 = min(15, max(0, a));
  j1 = min(15, max(0, a+1));
}
__global__ void k_up(const float* __restrict__ vm, float* __restrict__ vt){
  int idx = blockIdx.x*256+threadIdx.x;
  if(idx >= B2*NTK*INNR) return;
  int e = idx & 511, n = (idx>>9)&1023, b = idx>>19;
  int hm = n>>5, wm = n&31;
  int h0,h1,w0,w1; float fh,fw;
  up_wt(hm,h0,h1,fh); up_wt(wm,w0,w1,fw);
  const float* base = vm + (size_t)b*CTK*INNR + e;
  float v00=base[(size_t)(h0*16+w0)*INNR], v01=base[(size_t)(h0*16+w1)*INNR];
  float v10=base[(size_t)(h1*16+w0)*INNR], v11=base[(size_t)(h1*16+w1)*INNR];
  vt[((size_t)b*NTK+n)*INNR+e] = (1.f-fh)*((1.f-fw)*v00+fw*v01) + fh*((1.f-fw)*v10+fw*v11);
}

// ======================================================================================
// Workspace layout is computed at runtime from ws_size:
//   S = slices per chunk (16 if ws fits ~171 MB, else 4 -> 62.6 MB, proven envelope)
//   SHARED region (S*1048576 f32) time-shares: lgC -> Dq -> (FF phase) G
//   kv buffers are 2x (both weight-blocks precomputed upfront in ONE dispatch).
// ======================================================================================

extern "C" void kernel_launch(void* const* d_in, const int* in_sizes, int n_in,
                              void* d_out, int out_size, void* d_ws, size_t ws_size,
                              hipStream_t stream){
  const float* hidden = (const float*)d_in[0];
  const float* context= (const float*)d_in[1];
  const float* pose   = (const float*)d_in[2];
  const float* Wq  = (const float*)d_in[3];
  const float* Wk  = (const float*)d_in[4];
  const float* Wv  = (const float*)d_in[5];
  const float* Wa  = (const float*)d_in[6];
  const float* abias=(const float*)d_in[7];
  const float* qbias=(const float*)d_in[8];
  const float* dwcw=(const float*)d_in[9];
  const float* dwcb=(const float*)d_in[10];
  const float* Wo  = (const float*)d_in[11];
  const float* nw  = (const float*)d_in[12];
  const float* nb  = (const float*)d_in[13];
  const float* fw  = (const float*)d_in[14];
  const float* fb  = (const float*)d_in[15];
  const float* W1  = (const float*)d_in[16];
  const float* b1  = (const float*)d_in[17];
  const float* W2  = (const float*)d_in[18];
  const float* b2v = (const float*)d_in[19];

  float* ws = (float*)d_ws;
  const size_t wsfl = ws_size / 4;  // f32 units available

  // fixed = 6,610,944 f32; per-S = 2,260,992 f32
  int S;
  {
    const size_t need16 = 6610944ull + 16ull*2260992ull;   // 42,786,816 f32 ~ 171 MB
    S = (wsfl >= need16) ? 16 : 4;                          // S=4 -> 62.6 MB (proven)
  }
  const int NCH = 32 / S;

  size_t off = 0;
  auto take = [&](size_t n){ size_t o = off; off += n; return o; };
  float*  vm   = ws + take(262144);
  float*  vb   = ws + take(1048576);                 // 2x b
  float*  vt   = ws + take(2097152);                 // 2x b
  ushort* kbf  = (ushort*)(ws + take(524288));       // 2x b
  ushort* vbT  = (ushort*)(ws + take(524288));       // 2x b
  ushort* lnh  = (ushort*)(ws + take((size_t)S*163840));
  ushort* wkT  = (ushort*)(ws + take(524288));
  ushort* wvT  = (ushort*)(ws + take(524288));
  ushort* wqT  = (ushort*)(ws + take(163840));
  ushort* waT  = (ushort*)(ws + take(163840));
  ushort* woT  = (ushort*)(ws + take(163840));
  ushort* w1T  = (ushort*)(ws + take(409600));
  ushort* w2T  = (ushort*)(ws + take(204800));
  float*  SH   = ws + take((size_t)S*1048576);   // lgC / Dq / G (time-shared)
  ushort* atok = (ushort*)(ws + take((size_t)S*262144));
  ushort* akvT = (ushort*)(ws + take((size_t)S*262144));
  ushort* qbf  = (ushort*)(ws + take((size_t)S*262144));
  ushort* xbf  = (ushort*)(ws + take((size_t)S*262144));

  float* hs = (float*)d_out;

  hipMemcpyAsync(hs, hidden, (size_t)B2*TT*NTK*QD*sizeof(float),
                 hipMemcpyDeviceToDevice, stream);

  // one-time weight transpose+cvt to bf16 [N][K]
  for(int b=0;b<2;b++){
    k_wtrans<<<dim3(8,16),256,0,stream>>>(Wk+(size_t)b*CD*INNR,  wkT+(size_t)b*524288, CD, INNR);
    k_wtrans<<<dim3(8,16),256,0,stream>>>(Wv+(size_t)b*CD*INNR,  wvT+(size_t)b*524288, CD, INNR);
    k_wtrans<<<dim3(8,5), 256,0,stream>>>(Wq+(size_t)b*QD*INNR,  wqT+(size_t)b*163840, QD, INNR);
    k_wtrans<<<dim3(8,5), 256,0,stream>>>(Wa+(size_t)b*QD*INNR,  waT+(size_t)b*163840, QD, INNR);
    k_wtrans<<<dim3(5,8), 256,0,stream>>>(Wo+(size_t)b*INNR*QD,  woT+(size_t)b*163840, INNR, QD);
  }
  k_wtrans<<<dim3(40,5),256,0,stream>>>(W1, w1T, QD, 2560);
  k_wtrans<<<dim3(5,20),256,0,stream>>>(W2, w2T, 1280, QD);

  // hs-independent kv chain, BOTH weight-blocks, one big dispatch then conv/up per b
  g_kv<<<dim3(4,8,4),256,0,stream>>>(context, wkT, wvT, kbf, vb, vbT);
  for(int b=0;b<2;b++){
    k_conv<<<(B2*CTK*INNR)/256,256,0,stream>>>(vb + (size_t)b*524288,
        dwcw+(size_t)b*INNR*9, dwcb+(size_t)b*INNR, vm);
    k_up<<<(B2*NTK*INNR)/256,256,0,stream>>>(vm, vt + (size_t)b*1048576);
  }

  for(int b=0;b<2;b++){
    const ushort* kbf_b = kbf + (size_t)b*524288;
    const ushort* vbT_b = vbT + (size_t)b*524288;
    const float*  vt_b  = vt  + (size_t)b*1048576;
    for(int ch=0; ch<NCH; ch++){
      const int pt0 = ch*S;
      g_atok<<<dim3(4,8,S),256,0,stream>>>(pose, waT+(size_t)b*163840, atok, pt0);
      g_logits<<<dim3(2,8,2*S),256,0,stream>>>(atok, kbf_b, abias+(size_t)b*NTK*CTK, SH, pt0);
      k_softmax256<<<2*S*1024,256,0,stream>>>(SH);
      g_pvmax<<<dim3(4,8,S),256,0,stream>>>((const ushort*)SH, vbT_b, akvT, pt0);
      k_ln<<<S*1024,64,0,stream>>>(hs, nw, nb, lnh, pt0*1024);
      g_q<<<dim3(4,S*8),256,0,stream>>>(lnh, wqT+(size_t)b*163840, qbf);
      g_aql<<<dim3(8,8,S),256,0,stream>>>(qbf, atok, qbias+(size_t)b*NTK*NTK, SH);
      k_softmax1024<<<S*1024,256,0,stream>>>(SH);
      g_aqpv<<<dim3(4,8,S),256,0,stream>>>(SH, akvT, vt_b, xbf, pt0);
      g_wo<<<dim3(5,S*8),256,0,stream>>>(xbf, woT+(size_t)b*163840, hs, pt0*1024);
    }
  }

  for(int ch=0; ch<NCH; ch++){
    const int row0 = ch*S*1024;
    k_ln<<<S*1024,64,0,stream>>>(hs, fw, fb, lnh, row0);
    g_ff1<<<dim3(20,S*8),256,0,stream>>>(lnh, w1T, b1, (ushort*)SH);
    g_ff2<<<dim3(5,S*8),256,0,stream>>>((ushort*)SH, w2T, b2v, hs, row0);
  }
}

// Round 8
// 1246.530 us; speedup vs baseline: 1.1264x; 1.1264x over previous
//
#include <hip/hip_runtime.h>
#include <hip/hip_bf16.h>
#include <math.h>

typedef __hip_bfloat16 bf16;
typedef short short8 __attribute__((ext_vector_type(8)));
typedef float floatx4 __attribute__((ext_vector_type(4)));

// problem constants
static const int B2   = 2;
static const int TT   = 16;
static const int NTK  = 1024;
static const int CTK  = 256;
static const int QD   = 320;
static const int INNR = 512;
static const int CD   = 1024;
#define SCALE_ 0.125f

__device__ __forceinline__ ushort f2bu(float x){
  bf16 h = __float2bfloat16(x);
  return *reinterpret_cast<ushort*>(&h);
}

// ---- T1: XCD-aware bijective block swizzle (all GEMM grids are %8==0).
// Block with linear dispatch id `lin` (round-robin to XCD lin&7) executes work
// item (lin&7)*q + lin>>3 -> each XCD gets a CONTIGUOUS chunk of the work space,
// so same-row A-panels stay in that XCD's L2. Relabeling only: correctness-neutral.
#define XCD_SWZ \
  int bx, by, bz; { \
    const int gx=gridDim.x, gy=gridDim.y; \
    const int lin = blockIdx.x + gx*(blockIdx.y + gy*blockIdx.z); \
    const int q = (gx*gy*gridDim.z)>>3; \
    const int swz = (lin&7)*q + (lin>>3); \
    bx = swz % gx; const int r_ = swz / gx; by = r_ % gy; bz = r_ / gy; \
  }

// ======================================================================================
// LDS tile layout (per 32-k tile, rows x 32 bf16, NO pad):
//   us_off(row, q, t) = row*32 + ((q + (row>>1))&3)*8 + t     q = 16B chunk 0..3
// Conflict-free verified (R5/R6: SQ_LDS_BANK_CONFLICT = 0 on this pattern).
// Staging: T14 reg-based 1-DEEP (R6 proven; R7's 2-deep regressed: compiler emits
// conservative vmcnt that drains just-issued loads at the ds_write).
// ======================================================================================

// bf16 rows: row-major [rows][ld(us)], NV=2 -> 128 rows, NV=1 -> 64 rows.
template<int NV>
struct StBf {
  const ushort* src; int ld; int tid;
  short8 r[NV];
  __device__ __forceinline__ void load(int k0){
#pragma unroll
    for(int v=0;v<NV;v++){
      int idx=tid+v*256, rr=idx>>2, kq=idx&3;
      r[v] = *(const short8*)&src[(size_t)rr*ld + k0 + kq*8];
    }
  }
  __device__ __forceinline__ void store(ushort* dst){
#pragma unroll
    for(int v=0;v<NV;v++){
      int idx=tid+v*256, rr=idx>>2, kq=idx&3;
      *(short8*)&dst[rr*32 + ((kq+(rr>>1))&3)*8] = r[v];
    }
  }
};

// f32 rows (A of g_kv): reg-stage + cvt, swizzled ds_write
struct StT128 {
  const float* src; int ld; int tid;
  float4 r[4];
  __device__ __forceinline__ void load(int k0){
#pragma unroll
    for(int i=0;i<4;i++){
      int f4=tid+i*256, rr=f4>>3, kq=f4&7;
      r[i] = *(const float4*)(src + (size_t)rr*ld + k0 + kq*4);
    }
  }
  __device__ __forceinline__ void store(ushort* dst){
#pragma unroll
    for(int i=0;i<4;i++){
      int f4=tid+i*256, rr=f4>>3, kq=f4&7;
      int s=((kq>>1)+(rr>>1))&3;
      float4 v=r[i];
      ushort4 u={f2bu(v.x),f2bu(v.y),f2bu(v.z),f2bu(v.w)};
      *(ushort4*)&dst[rr*32 + s*8 + (kq&1)*4]=u;
    }
  }
};

// pose gather (A of g_atok): A[m][kk] = base[(k0+kk)*T*N + m], f32 + cvt, swizzled write
struct StAtok {
  const float* base; int tid;
  float r[16];
  __device__ __forceinline__ void load(int k0){
#pragma unroll
    for(int i=0;i<16;i++){
      int e=tid+i*256, m=e&127, kk=e>>7;
      r[i]=base[(size_t)(k0+kk)*(TT*NTK) + m];
    }
  }
  __device__ __forceinline__ void store(ushort* dst){
#pragma unroll
    for(int i=0;i<16;i++){
      int e=tid+i*256, m=e&127, kk=e>>7;
      int s=((kk>>3)+(m>>1))&3;
      dst[m*32 + s*8 + (kk&7)]=f2bu(r[i]);
    }
  }
};

// ============================ MFMA tile compute (swizzled read) ============================
template<int NT>
__device__ __forceinline__ void mfma_tiles(const ushort* As, const ushort* Bs,
    floatx4 (&acc)[4][NT], int mOff, int nOff, int lane15, int quad){
  short8 af[4], bfm[NT];
  #pragma unroll
  for(int i=0;i<4;i++){
    int ar = mOff + i*16 + lane15;
    af[i] = *(const short8*)&As[ar*32 + ((quad + (ar>>1))&3)*8];
  }
  #pragma unroll
  for(int j=0;j<NT;j++){
    int br = nOff + j*16 + lane15;
    bfm[j] = *(const short8*)&Bs[br*32 + ((quad + (br>>1))&3)*8];
  }
  #pragma unroll
  for(int i=0;i<4;i++)
    #pragma unroll
    for(int j=0;j<NT;j++)
      acc[i][j] = __builtin_amdgcn_mfma_f32_16x16x32_bf16(af[i], bfm[j], acc[i][j], 0, 0, 0);
}

template<int NT>
__device__ __forceinline__ void zero_acc(floatx4 (&acc)[4][NT]){
  floatx4 z = {0.f,0.f,0.f,0.f};
  #pragma unroll
  for(int i=0;i<4;i++)
    #pragma unroll
    for(int j=0;j<NT;j++) acc[i][j]=z;
}

// ===== 1-deep double-buffered K-loop (R6 proven): 1 barrier/iter; reg-loads of tile
// k+1 stay in flight across the barrier, cvt+ds_write after mfma(k). =====
template<int NT, class SA, class SB>
__device__ __forceinline__ void core_db(SA& sa, SB& sb, int K,
    ushort* As0, ushort* As1, ushort* Bs0, ushort* Bs1,
    floatx4 (&acc)[4][NT], int mOff, int nOff, int lane15, int quad){
  sa.load(0); sb.load(0);
  sa.store(As0); sb.store(Bs0);
  const int nk = K>>5;
  for(int i=0;i<nk-1;i++){
    sa.load((i+1)<<5); sb.load((i+1)<<5);
    __syncthreads();
    mfma_tiles<NT>((i&1)?As1:As0, (i&1)?Bs1:Bs0, acc, mOff,nOff,lane15,quad);
    sa.store((i&1)?As0:As1); sb.store((i&1)?Bs0:Bs1);
  }
  __syncthreads();
  mfma_tiles<NT>(((nk-1)&1)?As1:As0, ((nk-1)&1)?Bs1:Bs0, acc, mOff,nOff,lane15,quad);
}

#define GEMM_IDS(NT_) \
  const int tid=threadIdx.x, w=tid>>6, lane15=tid&15, quad=(tid>>4)&3; \
  const int mOff=(w&1)*64, nOff=(w>>1)*(NT_*16);
#define EPI(NT_) \
  _Pragma("unroll") for(int i=0;i<4;i++) \
  _Pragma("unroll") for(int j=0;j<NT_;j++) \
  _Pragma("unroll") for(int r=0;r<4;r++)
#define ROWG (mOff + i*16 + quad*4 + r)
#define COLG (nOff + j*16 + lane15)

// ---------------- one-time: W[K][N] f32 -> WT[N][K] bf16 (tiled transpose) ----------------
__global__ void __launch_bounds__(256) k_wtrans(const float* __restrict__ W, ushort* __restrict__ WT,
                                                int K, int N){
  __shared__ float t[64][65];
  const int kB = blockIdx.y*64, nB = blockIdx.x*64;
  for(int e=threadIdx.x; e<4096; e+=256){
    int r=e>>6, c=e&63;
    t[r][c] = W[(size_t)(kB+r)*N + nB+c];
  }
  __syncthreads();
  for(int e=threadIdx.x; e<4096; e+=256){
    int r=e>>6, c=e&63;
    WT[(size_t)(nB+r)*K + kB+c] = f2bu(t[c][r]);
  }
}

// ---------------- LN-apply -> bf16 rows ----------------
__global__ void k_ln(const float* __restrict__ hs, const float* __restrict__ w,
                     const float* __restrict__ b, ushort* __restrict__ out, int row0){
  const int r = blockIdx.x, lane = threadIdx.x;   // 64 threads
  const float* hr = hs + (size_t)(row0+r)*QD;
  float s=0.f, s2=0.f;
  #pragma unroll
  for(int j=0;j<5;j++){ float v=hr[j*64+lane]; s+=v; s2+=v*v; }
  #pragma unroll
  for(int o=32;o;o>>=1){ s+=__shfl_down(s,o); s2+=__shfl_down(s2,o); }
  s = __shfl(s,0); s2 = __shfl(s2,0);
  float mu=s*(1.f/320.f);
  float var=s2*(1.f/320.f)-mu*mu;
  float rs=rsqrtf(var+1e-5f);
  #pragma unroll
  for(int j=0;j<5;j++){
    int c=j*64+lane;
    out[(size_t)r*QD + c] = f2bu((hr[c]-mu)*rs*w[c]+b[c]);
  }
}

// ---------------- merged kv projection: z=(b, k/v)  (M=1024,N=512,K=1024) ----------------
__global__ void __launch_bounds__(256) g_kv(const float* __restrict__ A,
                                            const ushort* __restrict__ wkT, const ushort* __restrict__ wvT,
                                            ushort* __restrict__ kbf, float* __restrict__ vb,
                                            ushort* __restrict__ vbT){
  __shared__ ushort As[2][128*32], Bs[2][128*32];
  GEMM_IDS(4)
  XCD_SWZ
  const int z=bz, b=z>>1, isv=z&1;
  const ushort* BT = (isv ? wvT : wkT) + (size_t)b*524288;
  const int rB=by*128, cB=bx*128;
  floatx4 acc[4][4]; zero_acc<4>(acc);
  StT128 sa{A + (size_t)rB*CD, CD, tid};
  StBf<2> sb{BT + (size_t)cB*CD, CD, tid};
  core_db<4>(sa, sb, CD, As[0],As[1],Bs[0],Bs[1], acc, mOff,nOff,lane15,quad);
  if(!isv){
    ushort* kb = kbf + (size_t)b*524288;
    EPI(4){ kb[(size_t)(rB+ROWG)*INNR + cB+COLG] = f2bu(acc[i][j][r]); }
  }else{
    float* vf = vb + (size_t)b*524288;
    ushort* vT = vbT + (size_t)b*524288;
    EPI(4){
      int row=rB+ROWG, col=cB+COLG;
      float v=acc[i][j][r];
      vf[(size_t)row*INNR + col] = v;
      vT[((size_t)(row>>8)*INNR + col)*CTK + (row&255)] = f2bu(v);
    }
  }
}

// ---------------- a_tok: atok[z] = pose_t[pt0+z] @ Wa  (M=1024,N=512,K=320) ----------------
__global__ void __launch_bounds__(256) g_atok(const float* __restrict__ pose, const ushort* __restrict__ WaT,
                                              ushort* __restrict__ atok, int pt0){
  __shared__ ushort As[2][128*32], Bs[2][128*32];
  GEMM_IDS(4)
  XCD_SWZ
  const int z=bz, pt=pt0+z, bb=pt>>4, t=pt&15;
  const int rB=by*128, cB=bx*128;
  floatx4 acc[4][4]; zero_acc<4>(acc);
  StAtok sa{pose + ((size_t)(bb*QD)*TT + t)*NTK + rB, tid};
  StBf<2> sb{WaT + (size_t)cB*QD, QD, tid};
  core_db<4>(sa, sb, QD, As[0],As[1],Bs[0],Bs[1], acc, mOff,nOff,lane15,quad);
  EPI(4){ atok[((size_t)z*NTK + rB+ROWG)*INNR + cB+COLG] = f2bu(acc[i][j][r]); }
}

// ---------------- agent logits (NT) + scale + bias  (M=1024,N=256,K=512) ----------------
__global__ void __launch_bounds__(256) g_logits(const ushort* __restrict__ atok, const ushort* __restrict__ kbf,
                                                const float* __restrict__ abias, float* __restrict__ lgC, int pt0){
  __shared__ ushort As[2][128*32], Bs[2][128*32];
  GEMM_IDS(4)
  XCD_SWZ
  const int z=bz, zp=z>>1, c=z&1, pt=pt0+zp, bb=pt>>4;
  const int rB=by*128, cB=bx*128;
  floatx4 acc[4][4]; zero_acc<4>(acc);
  StBf<2> sa{atok + ((size_t)zp*NTK + rB)*INNR, INNR, tid};
  StBf<2> sb{kbf + (size_t)(bb*512 + 2*cB + c)*INNR, 2*INNR, tid};
  core_db<4>(sa, sb, INNR, As[0],As[1],Bs[0],Bs[1], acc, mOff,nOff,lane15,quad);
  float* Cz = lgC + (size_t)(zp*2+c)*NTK*CTK;
  EPI(4){
    int row=rB+ROWG, col=cB+COLG;
    Cz[(size_t)row*CTK + col] = acc[i][j][r]*SCALE_ + abias[(size_t)row*CTK + col];
  }
}

// ---------------- PV + frame max (NT via vT) + transposed bf16 out  (M=1024,N=512,K=256) ----
__global__ void __launch_bounds__(256) g_pvmax(const ushort* __restrict__ lg_us, const ushort* __restrict__ vT,
                                               ushort* __restrict__ akvT, int pt0){
  __shared__ ushort As[2][128*32], Bs[2][128*32];
  GEMM_IDS(4)
  XCD_SWZ
  const int zp=bz, pt=pt0+zp, bb=pt>>4;
  const int rB=by*128, cB=bx*128;
  floatx4 best[4][4]; zero_acc<4>(best);
  floatx4 acc[4][4];
  for(int c=0;c<2;c++){
    if(c) __syncthreads();
    zero_acc<4>(acc);
    StBf<2> sa{lg_us + ((size_t)(zp*2+c)*NTK + rB)*INNR, INNR, tid};   // in-place bf16, stride 512us
    StBf<2> sb{vT + ((size_t)(bb*2+c)*INNR + cB)*CTK, CTK, tid};
    core_db<4>(sa, sb, CTK, As[0],As[1],Bs[0],Bs[1], acc, mOff,nOff,lane15,quad);
    if(c==0){
      #pragma unroll
      for(int i=0;i<4;i++)
        #pragma unroll
        for(int j=0;j<4;j++) best[i][j]=acc[i][j];
    }else{
      EPI(4){ best[i][j][r] = fmaxf(best[i][j][r], acc[i][j][r]); }
    }
  }
  #pragma unroll
  for(int i=0;i<4;i++)
    #pragma unroll
    for(int j=0;j<4;j++){
      int col = cB + nOff + j*16 + lane15;
      int row0 = rB + mOff + i*16 + quad*4;
      ushort4 u = { f2bu(best[i][j][0]), f2bu(best[i][j][1]), f2bu(best[i][j][2]), f2bu(best[i][j][3]) };
      *(ushort4*)&akvT[((size_t)zp*INNR + col)*NTK + row0] = u;
    }
}

// ---------------- q = LNh @ Wq  (rows = S*1024, N=512, K=320) ----------------
__global__ void __launch_bounds__(256) g_q(const ushort* __restrict__ lnh, const ushort* __restrict__ WqT,
                                           ushort* __restrict__ qb){
  __shared__ ushort As[2][128*32], Bs[2][128*32];
  GEMM_IDS(4)
  XCD_SWZ
  const int rB=by*128, cB=bx*128;
  floatx4 acc[4][4]; zero_acc<4>(acc);
  StBf<2> sa{lnh + (size_t)rB*QD, QD, tid};
  StBf<2> sb{WqT + (size_t)cB*QD, QD, tid};
  core_db<4>(sa, sb, QD, As[0],As[1],Bs[0],Bs[1], acc, mOff,nOff,lane15,quad);
  EPI(4){ qb[(size_t)(rB+ROWG)*INNR + cB+COLG] = f2bu(acc[i][j][r]); }
}

// ---------------- query logits (NT) + scale + qbias  (M=1024,N=1024,K=512) ----------------
__global__ void __launch_bounds__(256) g_aql(const ushort* __restrict__ qb, const ushort* __restrict__ atok,
                                             const float* __restrict__ qbias, float* __restrict__ D){
  __shared__ ushort As[2][128*32], Bs[2][128*32];
  GEMM_IDS(4)
  XCD_SWZ
  const int z=bz;
  const int rB=by*128, cB=bx*128;
  floatx4 acc[4][4]; zero_acc<4>(acc);
  StBf<2> sa{qb + ((size_t)z*NTK + rB)*INNR, INNR, tid};
  StBf<2> sb{atok + ((size_t)z*NTK + cB)*INNR, INNR, tid};
  core_db<4>(sa, sb, INNR, As[0],As[1],Bs[0],Bs[1], acc, mOff,nOff,lane15,quad);
  float* Dz = D + (size_t)z*NTK*NTK;
  EPI(4){
    int row=rB+ROWG, col=cB+COLG;
    Dz[(size_t)row*NTK + col] = acc[i][j][r]*SCALE_ + qbias[(size_t)row*NTK + col];
  }
}

// ---------------- x = aq @ akv + v_tok  (M=1024,N=512,K=1024) ----------------
__global__ void __launch_bounds__(256) g_aqpv(const float* __restrict__ D, const ushort* __restrict__ akvT,
                                              const float* __restrict__ vt, ushort* __restrict__ xb, int pt0){
  __shared__ ushort As[2][128*32], Bs[2][128*32];
  GEMM_IDS(4)
  XCD_SWZ
  const int z=bz, pt=pt0+z, bb=pt>>4;
  const int rB=by*128, cB=bx*128;
  floatx4 acc[4][4]; zero_acc<4>(acc);
  StBf<2> sa{(const ushort*)D + (size_t)z*2097152 + (size_t)rB*2048, 2048, tid};  // in-place bf16 rows
  StBf<2> sb{akvT + ((size_t)z*INNR + cB)*NTK, NTK, tid};
  core_db<4>(sa, sb, NTK, As[0],As[1],Bs[0],Bs[1], acc, mOff,nOff,lane15,quad);
  EPI(4){
    int row=rB+ROWG, col=cB+COLG;
    xb[((size_t)z*NTK + row)*INNR + col] = f2bu(acc[i][j][r] + vt[((size_t)bb*NTK + row)*INNR + col]);
  }
}

// ---------------- hs += x @ Wo (BN=64)  (rows = S*1024, N=320, K=512) ----------------
__global__ void __launch_bounds__(256) g_wo(const ushort* __restrict__ xb, const ushort* __restrict__ WoT,
                                            float* __restrict__ hs, int row0){
  __shared__ ushort As[2][128*32], Bs[2][64*32];
  GEMM_IDS(2)
  XCD_SWZ
  const int rB=by*128, cB=bx*64;
  floatx4 acc[4][2]; zero_acc<2>(acc);
  StBf<2> sa{xb + (size_t)rB*INNR, INNR, tid};
  StBf<1> sb{WoT + (size_t)cB*INNR, INNR, tid};
  core_db<2>(sa, sb, INNR, As[0],As[1],Bs[0],Bs[1], acc, mOff,nOff,lane15,quad);
  EPI(2){
    size_t o = (size_t)(row0+rB+ROWG)*QD + cB+COLG;
    hs[o] = hs[o] + acc[i][j][r];
  }
}

// ---------------- FF1 GEGLU (dual-B, BN=64)  (rows = S*1024, N=1280, K=320) ----------------
__global__ void __launch_bounds__(256) g_ff1(const ushort* __restrict__ lnh, const ushort* __restrict__ W1T,
    const float* __restrict__ b1, ushort* __restrict__ G){
  __shared__ ushort As[2][128*32], Ba[2][64*32], Bg[2][64*32];
  GEMM_IDS(2)
  XCD_SWZ
  const int rB=by*128, cB=bx*64;
  floatx4 accA[4][2], accG[4][2]; zero_acc<2>(accA); zero_acc<2>(accG);
  StBf<2> sa{lnh + (size_t)rB*QD, QD, tid};
  StBf<1> s1{W1T + (size_t)cB*QD, QD, tid};
  StBf<1> s2{W1T + (size_t)(1280+cB)*QD, QD, tid};
  sa.load(0); s1.load(0); s2.load(0);
  sa.store(As[0]); s1.store(Ba[0]); s2.store(Bg[0]);
  const int nk = QD>>5;  // 10
  for(int i=0;i<nk-1;i++){
    int k=(i+1)<<5;
    sa.load(k); s1.load(k); s2.load(k);
    __syncthreads();
    const int cur=i&1;
    mfma_tiles<2>(As[cur],Ba[cur],accA,mOff,nOff,lane15,quad);
    mfma_tiles<2>(As[cur],Bg[cur],accG,mOff,nOff,lane15,quad);
    sa.store(As[cur^1]); s1.store(Ba[cur^1]); s2.store(Bg[cur^1]);
  }
  __syncthreads();
  {
    const int cur=(nk-1)&1;
    mfma_tiles<2>(As[cur],Ba[cur],accA,mOff,nOff,lane15,quad);
    mfma_tiles<2>(As[cur],Bg[cur],accG,mOff,nOff,lane15,quad);
  }
  EPI(2){
    int n = cB+COLG;
    float a = accA[i][j][r] + b1[n];
    float g = accG[i][j][r] + b1[1280+n];
    G[(size_t)(rB+ROWG)*1280 + n] = f2bu(a*0.5f*g*(1.0f+erff(g*0.70710678f)));
  }
}

// ---------------- FF2 + bias + residual  (rows = S*1024, N=320, K=1280) ----------------
__global__ void __launch_bounds__(256) g_ff2(const ushort* __restrict__ G, const ushort* __restrict__ W2T,
    const float* __restrict__ b2v, float* __restrict__ hs, int row0){
  __shared__ ushort As[2][128*32], Bs[2][64*32];
  GEMM_IDS(2)
  XCD_SWZ
  const int rB=by*128, cB=bx*64;
  floatx4 acc[4][2]; zero_acc<2>(acc);
  StBf<2> sa{G + (size_t)rB*1280, 1280, tid};
  StBf<1> sb{W2T + (size_t)cB*1280, 1280, tid};
  core_db<2>(sa, sb, 1280, As[0],As[1],Bs[0],Bs[1], acc, mOff,nOff,lane15,quad);
  EPI(2){
    int col = cB+COLG;
    size_t o = (size_t)(row0+rB+ROWG)*QD + col;
    hs[o] = acc[i][j][r] + b2v[col] + hs[o];
  }
}

// ---------------- softmax over rows of 256: f32 in, bf16 out (in-place row head) ----------------
__global__ void k_softmax256(float* __restrict__ buf){
  __shared__ float red[8];
  const int tid=threadIdx.x;
  size_t row=blockIdx.x;
  float x = buf[row*256+tid];
  float m = x;
  #pragma unroll
  for(int o=32;o;o>>=1) m=fmaxf(m,__shfl_down(m,o));
  if((tid&63)==0) red[tid>>6]=m;
  __syncthreads();
  if(tid==0) red[4]=fmaxf(fmaxf(red[0],red[1]),fmaxf(red[2],red[3]));
  __syncthreads();
  float M=red[4];
  float e=__expf(x-M);
  float s=e;
  #pragma unroll
  for(int o=32;o;o>>=1) s+=__shfl_down(s,o);
  if((tid&63)==0) red[tid>>6]=s;
  __syncthreads();
  if(tid==0) red[5]=red[0]+red[1]+red[2]+red[3];
  __syncthreads();
  ((ushort*)buf)[row*512 + tid] = f2bu(e/red[5]);
}

// ---------------- softmax over rows of 1024: f32 in, bf16 out (in-place row head) ----------------
__global__ void k_softmax1024(float* __restrict__ buf){
  __shared__ float red[8];
  const int tid=threadIdx.x;
  size_t row=blockIdx.x;
  float4* p = (float4*)(buf + row*1024);
  float4 v = p[tid];
  float m = fmaxf(fmaxf(v.x,v.y),fmaxf(v.z,v.w));
  #pragma unroll
  for(int o=32;o;o>>=1) m=fmaxf(m,__shfl_down(m,o));
  if((tid&63)==0) red[tid>>6]=m;
  __syncthreads();
  if(tid==0) red[4]=fmaxf(fmaxf(red[0],red[1]),fmaxf(red[2],red[3]));
  __syncthreads();
  float M=red[4];
  v.x=__expf(v.x-M); v.y=__expf(v.y-M); v.z=__expf(v.z-M); v.w=__expf(v.w-M);
  float s=v.x+v.y+v.z+v.w;
  #pragma unroll
  for(int o=32;o;o>>=1) s+=__shfl_down(s,o);
  if((tid&63)==0) red[tid>>6]=s;
  __syncthreads();
  if(tid==0) red[5]=red[0]+red[1]+red[2]+red[3];
  __syncthreads();
  float inv=1.0f/red[5];
  ushort4 u = { f2bu(v.x*inv), f2bu(v.y*inv), f2bu(v.z*inv), f2bu(v.w*inv) };
  *(ushort4*)((ushort*)buf + row*2048 + (size_t)tid*4) = u;
}

// ---------------- depthwise 3x3 conv (SAME) + max over frames ----------------
__global__ void k_conv(const float* __restrict__ vbuf, const float* __restrict__ w3,
                       const float* __restrict__ wb, float* __restrict__ vm){
  int idx = blockIdx.x*256+threadIdx.x;
  if(idx >= B2*CTK*INNR) return;
  int e = idx & 511, hw = (idx>>9)&255, b = idx>>17;
  int h = hw>>4, w = hw&15;
  float wt[9];
  #pragma unroll
  for(int q=0;q<9;q++) wt[q]=w3[e*9+q];
  float bias = wb[e];
  float best=0.f;
  for(int c=0;c<2;c++){
    float s = bias;
    #pragma unroll
    for(int dy=-1;dy<=1;dy++)
      #pragma unroll
      for(int dx=-1;dx<=1;dx++){
        int hh=h+dy, ww=w+dx;
        if(hh>=0&&hh<16&&ww>=0&&ww<16)
          s += wt[(dy+1)*3+(dx+1)]*vbuf[((size_t)(b*2+c)*CTK + hh*16+ww)*INNR + e];
      }
    best = c ? fmaxf(best,s) : s;
  }
  vm[((size_t)b*CTK + hw)*INNR + e] = best;
}

// ---------------- bilinear x2 upsample (half-pixel, edge clamp) ----------------
__device__ __forceinline__ void up_wt(int i, int& j0, int& j1, float& w){
  float s = 0.5f*i - 0.25f;
  float f = floorf(s);
  w = s - f;
  int a = (int)f;
  j0 = min(15, max(0, a));
  j1 = min(15, max(0, a+1));
}
__global__ void k_up(const float* __restrict__ vm, float* __restrict__ vt){
  int idx = blockIdx.x*256+threadIdx.x;
  if(idx >= B2*NTK*INNR) return;
  int e = idx & 511, n = (idx>>9)&1023, b = idx>>19;
  int hm = n>>5, wm = n&31;
  int h0,h1,w0,w1; float fh,fw;
  up_wt(hm,h0,h1,fh); up_wt(wm,w0,w1,fw);
  const float* base = vm + (size_t)b*CTK*INNR + e;
  float v00=base[(size_t)(h0*16+w0)*INNR], v01=base[(size_t)(h0*16+w1)*INNR];
  float v10=base[(size_t)(h1*16+w0)*INNR], v11=base[(size_t)(h1*16+w1)*INNR];
  vt[((size_t)b*NTK+n)*INNR+e] = (1.f-fh)*((1.f-fw)*v00+fw*v01) + fh*((1.f-fw)*v10+fw*v11);
}

// ======================================================================================
// Workspace layout is computed at runtime from ws_size:
//   S = slices per chunk (16 if ws fits ~171 MB, else 4 -> 62.6 MB, proven envelope)
//   SHARED region (S*1048576 f32) time-shares: lgC -> Dq -> (FF phase) G
//   kv buffers are 2x (both weight-blocks precomputed upfront in ONE dispatch).
// ======================================================================================

extern "C" void kernel_launch(void* const* d_in, const int* in_sizes, int n_in,
                              void* d_out, int out_size, void* d_ws, size_t ws_size,
                              hipStream_t stream){
  const float* hidden = (const float*)d_in[0];
  const float* context= (const float*)d_in[1];
  const float* pose   = (const float*)d_in[2];
  const float* Wq  = (const float*)d_in[3];
  const float* Wk  = (const float*)d_in[4];
  const float* Wv  = (const float*)d_in[5];
  const float* Wa  = (const float*)d_in[6];
  const float* abias=(const float*)d_in[7];
  const float* qbias=(const float*)d_in[8];
  const float* dwcw=(const float*)d_in[9];
  const float* dwcb=(const float*)d_in[10];
  const float* Wo  = (const float*)d_in[11];
  const float* nw  = (const float*)d_in[12];
  const float* nb  = (const float*)d_in[13];
  const float* fw  = (const float*)d_in[14];
  const float* fb  = (const float*)d_in[15];
  const float* W1  = (const float*)d_in[16];
  const float* b1  = (const float*)d_in[17];
  const float* W2  = (const float*)d_in[18];
  const float* b2v = (const float*)d_in[19];

  float* ws = (float*)d_ws;
  const size_t wsfl = ws_size / 4;  // f32 units available

  // fixed = 6,610,944 f32; per-S = 2,260,992 f32
  int S;
  {
    const size_t need16 = 6610944ull + 16ull*2260992ull;   // 42,786,816 f32 ~ 171 MB
    S = (wsfl >= need16) ? 16 : 4;                          // S=4 -> 62.6 MB (proven)
  }
  const int NCH = 32 / S;

  size_t off = 0;
  auto take = [&](size_t n){ size_t o = off; off += n; return o; };
  float*  vm   = ws + take(262144);
  float*  vb   = ws + take(1048576);                 // 2x b
  float*  vt   = ws + take(2097152);                 // 2x b
  ushort* kbf  = (ushort*)(ws + take(524288));       // 2x b
  ushort* vbT  = (ushort*)(ws + take(524288));       // 2x b
  ushort* lnh  = (ushort*)(ws + take((size_t)S*163840));
  ushort* wkT  = (ushort*)(ws + take(524288));
  ushort* wvT  = (ushort*)(ws + take(524288));
  ushort* wqT  = (ushort*)(ws + take(163840));
  ushort* waT  = (ushort*)(ws + take(163840));
  ushort* woT  = (ushort*)(ws + take(163840));
  ushort* w1T  = (ushort*)(ws + take(409600));
  ushort* w2T  = (ushort*)(ws + take(204800));
  float*  SH   = ws + take((size_t)S*1048576);   // lgC / Dq / G (time-shared)
  ushort* atok = (ushort*)(ws + take((size_t)S*262144));
  ushort* akvT = (ushort*)(ws + take((size_t)S*262144));
  ushort* qbf  = (ushort*)(ws + take((size_t)S*262144));
  ushort* xbf  = (ushort*)(ws + take((size_t)S*262144));

  float* hs = (float*)d_out;

  hipMemcpyAsync(hs, hidden, (size_t)B2*TT*NTK*QD*sizeof(float),
                 hipMemcpyDeviceToDevice, stream);

  // one-time weight transpose+cvt to bf16 [N][K]
  for(int b=0;b<2;b++){
    k_wtrans<<<dim3(8,16),256,0,stream>>>(Wk+(size_t)b*CD*INNR,  wkT+(size_t)b*524288, CD, INNR);
    k_wtrans<<<dim3(8,16),256,0,stream>>>(Wv+(size_t)b*CD*INNR,  wvT+(size_t)b*524288, CD, INNR);
    k_wtrans<<<dim3(8,5), 256,0,stream>>>(Wq+(size_t)b*QD*INNR,  wqT+(size_t)b*163840, QD, INNR);
    k_wtrans<<<dim3(8,5), 256,0,stream>>>(Wa+(size_t)b*QD*INNR,  waT+(size_t)b*163840, QD, INNR);
    k_wtrans<<<dim3(5,8), 256,0,stream>>>(Wo+(size_t)b*INNR*QD,  woT+(size_t)b*163840, INNR, QD);
  }
  k_wtrans<<<dim3(40,5),256,0,stream>>>(W1, w1T, QD, 2560);
  k_wtrans<<<dim3(5,20),256,0,stream>>>(W2, w2T, 1280, QD);

  // hs-independent kv chain, BOTH weight-blocks, one big dispatch then conv/up per b
  g_kv<<<dim3(4,8,4),256,0,stream>>>(context, wkT, wvT, kbf, vb, vbT);
  for(int b=0;b<2;b++){
    k_conv<<<(B2*CTK*INNR)/256,256,0,stream>>>(vb + (size_t)b*524288,
        dwcw+(size_t)b*INNR*9, dwcb+(size_t)b*INNR, vm);
    k_up<<<(B2*NTK*INNR)/256,256,0,stream>>>(vm, vt + (size_t)b*1048576);
  }

  for(int b=0;b<2;b++){
    const ushort* kbf_b = kbf + (size_t)b*524288;
    const ushort* vbT_b = vbT + (size_t)b*524288;
    const float*  vt_b  = vt  + (size_t)b*1048576;
    for(int ch=0; ch<NCH; ch++){
      const int pt0 = ch*S;
      g_atok<<<dim3(4,8,S),256,0,stream>>>(pose, waT+(size_t)b*163840, atok, pt0);
      g_logits<<<dim3(2,8,2*S),256,0,stream>>>(atok, kbf_b, abias+(size_t)b*NTK*CTK, SH, pt0);
      k_softmax256<<<2*S*1024,256,0,stream>>>(SH);
      g_pvmax<<<dim3(4,8,S),256,0,stream>>>((const ushort*)SH, vbT_b, akvT, pt0);
      k_ln<<<S*1024,64,0,stream>>>(hs, nw, nb, lnh, pt0*1024);
      g_q<<<dim3(4,S*8),256,0,stream>>>(lnh, wqT+(size_t)b*163840, qbf);
      g_aql<<<dim3(8,8,S),256,0,stream>>>(qbf, atok, qbias+(size_t)b*NTK*NTK, SH);
      k_softmax1024<<<S*1024,256,0,stream>>>(SH);
      g_aqpv<<<dim3(4,8,S),256,0,stream>>>(SH, akvT, vt_b, xbf, pt0);
      g_wo<<<dim3(5,S*8),256,0,stream>>>(xbf, woT+(size_t)b*163840, hs, pt0*1024);
    }
  }

  for(int ch=0; ch<NCH; ch++){
    const int row0 = ch*S*1024;
    k_ln<<<S*1024,64,0,stream>>>(hs, fw, fb, lnh, row0);
    g_ff1<<<dim3(20,S*8),256,0,stream>>>(lnh, w1T, b1, (ushort*)SH);
    g_ff2<<<dim3(5,S*8),256,0,stream>>>((ushort*)SH, w2T, b2v, hs, row0);
  }
}